// Round 7
// baseline (114.053 us; speedup 1.0000x reference)
//
#include <hip/hip_runtime.h>
#include <hip/hip_bf16.h>

#define MAXO 25
#define WCHUNK 512    // timesteps per wave (8 rounds of 64)
#define BCHUNK 2048   // timesteps per block (4 waves)

// flags[bid]: bits31:30 = state (0=invalid, 1=aggregate, 2=inclusive),
//             bits29:0  = count of ones
#define FLAG_AGG (1u << 30)
#define FLAG_INC (2u << 30)
#define FLAG_VAL 0x3FFFFFFFu

// ---------------------------------------------------------------------------
// Single-pass fused kernel with windowed decoupled lookback (rocPRIM-style).
// ---------------------------------------------------------------------------
__global__ __launch_bounds__(256, 4) void pda_lookback(
    const int* __restrict__ seq, unsigned* __restrict__ flags,
    const float* __restrict__ delta, const float* __restrict__ scale_p,
    float* __restrict__ out, int T)
{
    __shared__ __align__(16) float stage[4][64 * MAXO];  // 25.6 KB, per-wave slices
    __shared__ unsigned wsum[4];
    __shared__ unsigned s_excl;

    const int lane = threadIdx.x & 63;
    const int wid  = threadIdx.x >> 6;
    const int bid  = blockIdx.x;
    const long wbase = (long)bid * BCHUNK + (long)wid * WCHUNK;

    // --- Phase A: load my wave's 512 bits once; keep ballot masks ---
    unsigned long long m[8];
    unsigned mycnt = 0;
    #pragma unroll
    for (int r = 0; r < 8; ++r) {
        long t = wbase + (long)r * 64 + lane;
        int b = (t < (long)T) ? seq[t] : 0;
        m[r] = __ballot(b != 0);
        mycnt += (unsigned)__popcll(m[r]);     // uniform across the wave
    }
    if (lane == 0) wsum[wid] = mycnt;
    __syncthreads();

    const unsigned bsum = wsum[0] + wsum[1] + wsum[2] + wsum[3];

    // publish aggregate immediately (block 0's aggregate IS its inclusive)
    if (threadIdx.x == 0) {
        unsigned tag = (bid == 0) ? FLAG_INC : FLAG_AGG;
        __hip_atomic_store(&flags[bid], tag | bsum, __ATOMIC_RELEASE,
                           __HIP_MEMORY_SCOPE_AGENT);
    }

    // --- wave 0: windowed lookback over predecessors, 64 flags at a time ---
    if (wid == 0) {
        unsigned excl = 0;
        if (bid > 0) {
            int j = bid - 1;                       // highest unresolved predecessor
            for (;;) {
                int  idx = j - lane;               // lane 0 reads the highest idx
                bool vl  = (idx >= 0);
                unsigned f;
                do {
                    f = vl ? __hip_atomic_load(&flags[idx], __ATOMIC_ACQUIRE,
                                               __HIP_MEMORY_SCOPE_AGENT)
                           : 0u;
                } while (__any(vl && f == 0u));

                unsigned long long inc_mask = __ballot(vl && (f >> 30) == 2u);
                unsigned contrib;
                bool done;
                if (inc_mask) {
                    // lowest lane number = highest block idx with an inclusive
                    int flead = (int)(__ffsll((long long)inc_mask) - 1);
                    contrib = (vl && lane <= flead) ? (f & FLAG_VAL) : 0u;
                    done = true;
                } else {
                    contrib = vl ? (f & FLAG_VAL) : 0u;
                    done = false;
                }
                #pragma unroll
                for (int off = 32; off; off >>= 1)
                    contrib += __shfl_down(contrib, off, 64);
                excl += __shfl(contrib, 0, 64);

                if (done) break;
                j -= 64;
                if (j < 0) break;                  // safety (block 0 is state-2)
            }
            if (lane == 0)
                __hip_atomic_store(&flags[bid], FLAG_INC | (excl + bsum),
                                   __ATOMIC_RELEASE, __HIP_MEMORY_SCOPE_AGENT);
        }
        if (lane == 0) s_excl = excl;
    }
    __syncthreads();

    const float d0 = delta[0];
    const float dd = delta[1] - d0;
    const float scale = scale_p[0];
    const float inv_denom = 1.0f / (24.0f + 1e-6f);

    unsigned run = s_excl;
    for (int w = 0; w < wid; ++w) run += wsum[w];

    const unsigned long long le_mask = (lane == 63) ? ~0ULL : ((2ULL << lane) - 1ULL);

    for (int r = 0; r < 8; ++r) {
        const long rbase = wbase + (long)r * 64;
        const long t = rbase + lane;

        unsigned ones_incl = run + (unsigned)__popcll(m[r] & le_mask);

        // counter = (t+1)*d0 + ones*(d1-d0)  (exact for this data)
        float c   = (float)(t + 1) * d0 + (float)ones_incl * dd;
        float z   = 10.0f * (c * inv_denom - 0.5f);
        float sig = 1.0f / (1.0f + __expf(-z));
        float cs  = sig * 24.0f;

        float w[MAXO];
        float sum = 0.0f;
        #pragma unroll
        for (int j = 0; j < MAXO; ++j) {
            float dist = fabsf((float)j - cs);
            w[j] = __expf(-scale * dist);
            sum += w[j];
        }
        float inv = 1.0f / sum;

        // Per-wave private LDS slice: no block barrier needed.
        #pragma unroll
        for (int j = 0; j < MAXO; ++j)
            stage[wid][lane * MAXO + j] = w[j] * inv;   // stride 25: conflict-free

        long rem = (long)T - rbase;
        int V = (rem >= 64) ? 64 : (rem < 0 ? 0 : (int)rem);

        if (V == 64) {
            float4* o4 = (float4*)(out + rbase * MAXO);            // 6400B-aligned
            const float4* s4 = (const float4*)&stage[wid][0];
            #pragma unroll
            for (int s = 0; s < 6; ++s)
                o4[s * 64 + lane] = s4[s * 64 + lane];
            if (lane < 16) o4[384 + lane] = s4[384 + lane];
        } else if (V > 0) {
            int F = V * MAXO;
            for (int f = lane; f < F; f += 64)
                out[rbase * MAXO + f] = stage[wid][f];
        }

        run += (unsigned)__popcll(m[r]);
    }
}

// ---------------------------------------------------------------------------
extern "C" void kernel_launch(void* const* d_in, const int* in_sizes, int n_in,
                              void* d_out, int out_size, void* d_ws, size_t ws_size,
                              hipStream_t stream)
{
    const float* delta   = (const float*)d_in[0];
    const float* scale_p = (const float*)d_in[1];
    const int*   seq     = (const int*)d_in[2];
    const int T = in_sizes[2];
    const int nblocks = (T + BCHUNK - 1) / BCHUNK;

    unsigned* flags = (unsigned*)d_ws;   // nblocks * 4 bytes

    hipMemsetAsync(flags, 0, (size_t)nblocks * sizeof(unsigned), stream);
    pda_lookback<<<nblocks, 256, 0, stream>>>(seq, flags, delta, scale_p,
                                              (float*)d_out, T);
}

// Round 8
// 43.979 us; speedup vs baseline: 2.5934x; 2.5934x over previous
//
#include <hip/hip_runtime.h>
#include <hip/hip_bf16.h>

#define MAXO 25
#define WCHUNK 512    // timesteps per wave (8 rounds of 64)
#define BCHUNK 2048   // timesteps per block (4 waves)

// ---------------------------------------------------------------------------
// Pass 1: per-wave 512-bit bitmap (8 x u64, bit index == time offset) and
// per-wave one-count. Lane L loads times [8L, 8L+8) as two int4s, builds a
// byte, then groups of 8 lanes OR-assemble each u64 word via shfl_xor.
// ---------------------------------------------------------------------------
__global__ __launch_bounds__(256) void pda_pass1(
    const int* __restrict__ seq, unsigned long long* __restrict__ masks,
    unsigned* __restrict__ wave_sums, int T)
{
    const int lane = threadIdx.x & 63;
    const int wid  = threadIdx.x >> 6;
    const int gwid = blockIdx.x * 4 + wid;
    const long base = (long)gwid * WCHUNK + (long)lane * 8;

    unsigned byte = 0;
    if (base + 8 <= (long)T) {
        const int4* p4 = (const int4*)(seq + base);   // 32B-aligned
        int4 a = p4[0], b = p4[1];
        byte =  (unsigned)(a.x & 1)        | ((unsigned)(a.y & 1) << 1)
             | ((unsigned)(a.z & 1) << 2)  | ((unsigned)(a.w & 1) << 3)
             | ((unsigned)(b.x & 1) << 4)  | ((unsigned)(b.y & 1) << 5)
             | ((unsigned)(b.z & 1) << 6)  | ((unsigned)(b.w & 1) << 7);
    } else {
        for (int k = 0; k < 8; ++k) {
            long t = base + k;
            if (t < (long)T) byte |= (unsigned)(seq[t] & 1) << k;
        }
    }

    // word w covers times [64w, 64w+64); lane L contributes bits (L&7)*8..+7
    unsigned long long v = (unsigned long long)byte << ((lane & 7) * 8);
    v |= __shfl_xor(v, 1, 64);
    v |= __shfl_xor(v, 2, 64);
    v |= __shfl_xor(v, 4, 64);
    if ((lane & 7) == 0)
        masks[(size_t)gwid * 8 + (lane >> 3)] = v;

    unsigned s = __popc(byte);
    #pragma unroll
    for (int off = 32; off; off >>= 1) s += __shfl_down(s, off, 64);
    if (lane == 0) wave_sums[gwid] = s;
}

// ---------------------------------------------------------------------------
// Pass 2 (main): no seq access, no ballots, no __syncthreads. Each wave:
// lane-strided prefix over wave_sums[0..gwid), load its 8 mask words, then
// counter -> soft_clamp -> 25-way softmax -> per-wave LDS stage -> coalesced
// float4 stores.
// ---------------------------------------------------------------------------
__global__ __launch_bounds__(256) void pda_main(
    const unsigned long long* __restrict__ masks,
    const unsigned* __restrict__ wave_sums,
    const float* __restrict__ delta, const float* __restrict__ scale_p,
    float* __restrict__ out, int T)
{
    __shared__ __align__(16) float stage[4][64 * MAXO];  // 25.6 KB, per-wave slices

    const int lane = threadIdx.x & 63;
    const int wid  = threadIdx.x >> 6;
    const int gwid = blockIdx.x * 4 + wid;
    const long wbase = (long)gwid * WCHUNK;

    const float d0 = delta[0];
    const float dd = delta[1] - d0;
    const float scale = scale_p[0];
    const float inv_denom = 1.0f / (24.0f + 1e-6f);

    // --- prefix of ones over all preceding waves (L2-hot, <=62 iters) ---
    unsigned p = 0;
    for (int i = lane; i < gwid; i += 64) p += wave_sums[i];
    #pragma unroll
    for (int off = 32; off; off >>= 1) p += __shfl_down(p, off, 64);
    unsigned run = __shfl(p, 0, 64);

    // --- this wave's 8 bitmap words (wave-uniform broadcast loads) ---
    unsigned long long m[8];
    const unsigned long long* mp = masks + (size_t)gwid * 8;
    #pragma unroll
    for (int r = 0; r < 8; ++r) m[r] = mp[r];

    const unsigned long long le_mask = (lane == 63) ? ~0ULL : ((2ULL << lane) - 1ULL);

    for (int r = 0; r < 8; ++r) {
        const long rbase = wbase + (long)r * 64;
        const long t = rbase + lane;

        unsigned ones_incl = run + (unsigned)__popcll(m[r] & le_mask);

        // counter = (t+1)*d0 + ones*(d1-d0)  (exact for this data)
        float c   = (float)(t + 1) * d0 + (float)ones_incl * dd;
        float z   = 10.0f * (c * inv_denom - 0.5f);
        float sig = 1.0f / (1.0f + __expf(-z));
        float cs  = sig * 24.0f;

        float w[MAXO];
        float sum = 0.0f;
        #pragma unroll
        for (int j = 0; j < MAXO; ++j) {
            float dist = fabsf((float)j - cs);
            w[j] = __expf(-scale * dist);
            sum += w[j];
        }
        float inv = 1.0f / sum;

        // Per-wave private LDS slice: intra-wave ds_write -> ds_read ->
        // global_store ordering is handled by compiler waitcnts.
        #pragma unroll
        for (int j = 0; j < MAXO; ++j)
            stage[wid][lane * MAXO + j] = w[j] * inv;   // stride 25: conflict-free

        long rem = (long)T - rbase;
        int V = (rem >= 64) ? 64 : (rem < 0 ? 0 : (int)rem);

        if (V == 64) {
            float4* o4 = (float4*)(out + rbase * MAXO);            // 6400B-aligned
            const float4* s4 = (const float4*)&stage[wid][0];
            #pragma unroll
            for (int s = 0; s < 6; ++s)
                o4[s * 64 + lane] = s4[s * 64 + lane];
            if (lane < 16) o4[384 + lane] = s4[384 + lane];
        } else if (V > 0) {
            int F = V * MAXO;
            for (int f = lane; f < F; f += 64)
                out[rbase * MAXO + f] = stage[wid][f];
        }

        run += (unsigned)__popcll(m[r]);
    }
}

// ---------------------------------------------------------------------------
extern "C" void kernel_launch(void* const* d_in, const int* in_sizes, int n_in,
                              void* d_out, int out_size, void* d_ws, size_t ws_size,
                              hipStream_t stream)
{
    const float* delta   = (const float*)d_in[0];
    const float* scale_p = (const float*)d_in[1];
    const int*   seq     = (const int*)d_in[2];
    const int T = in_sizes[2];
    const int nblocks = (T + BCHUNK - 1) / BCHUNK;
    const int nwaves  = nblocks * 4;

    // d_ws layout: [masks: nwaves*8 u64][wave_sums: nwaves u32]
    unsigned long long* masks = (unsigned long long*)d_ws;
    unsigned* wave_sums = (unsigned*)(masks + (size_t)nwaves * 8);

    pda_pass1<<<nblocks, 256, 0, stream>>>(seq, masks, wave_sums, T);
    pda_main <<<nblocks, 256, 0, stream>>>(masks, wave_sums, delta, scale_p,
                                           (float*)d_out, T);
}

// Round 9
// 43.423 us; speedup vs baseline: 2.6265x; 1.0128x over previous
//
#include <hip/hip_runtime.h>
#include <hip/hip_bf16.h>

#define MAXO 25
#define WCHUNK 512    // timesteps per wave (8 rounds of 64)
#define BCHUNK 2048   // timesteps per block (4 waves)

// ---------------------------------------------------------------------------
// Pass 1: per-BLOCK count of ones (2048 timesteps per block).
// ---------------------------------------------------------------------------
__global__ __launch_bounds__(256) void pda_sums(
    const int* __restrict__ seq, unsigned* __restrict__ blk_sums, int T)
{
    __shared__ unsigned ws[4];
    const int lane = threadIdx.x & 63;
    const int wid  = threadIdx.x >> 6;

    const long t0 = (long)blockIdx.x * BCHUNK + (long)wid * WCHUNK + (long)lane * 8;
    unsigned s = 0;
    if (t0 + 8 <= (long)T) {
        const int4* p = (const int4*)(seq + t0);   // 32B-aligned
        int4 a = p[0], b = p[1];
        s = (unsigned)(a.x + a.y + a.z + a.w + b.x + b.y + b.z + b.w);
    } else {
        for (int k = 0; k < 8; ++k) {
            long t = t0 + k;
            if (t < (long)T) s += (unsigned)seq[t];
        }
    }
    #pragma unroll
    for (int off = 32; off; off >>= 1) s += __shfl_down(s, off, 64);
    if (lane == 0) ws[wid] = s;
    __syncthreads();
    if (threadIdx.x == 0)
        blk_sums[blockIdx.x] = ws[0] + ws[1] + ws[2] + ws[3];
}

// ---------------------------------------------------------------------------
// Pass 2 (main): R5 structure, but softmax via closed-form geometric table:
//   exp(-s*|j-c|) = (j<=k ? a : b) * r^floor(|j-c|),  r = exp(-s)
//   denominator = a*(1-r^{k+1})/(1-r) + b*(1-r^{24-k})/(1-r)
// 2 exps per timestep instead of 25.
// ---------------------------------------------------------------------------
__global__ __launch_bounds__(256) void pda_main(
    const int* __restrict__ seq, const unsigned* __restrict__ blk_sums,
    const float* __restrict__ delta, const float* __restrict__ scale_p,
    float* __restrict__ out, int T)
{
    __shared__ __align__(16) float stage[4][64 * MAXO];  // 25.6 KB, per-wave slices
    __shared__ float tab[26];                            // r^0 .. r^25
    __shared__ unsigned wsum[4];
    __shared__ unsigned bpart[4];

    const int lane = threadIdx.x & 63;
    const int wid  = threadIdx.x >> 6;
    const int bid  = blockIdx.x;
    const long wbase = (long)bid * BCHUNK + (long)wid * WCHUNK;

    const float d0 = delta[0];
    const float dd = delta[1] - d0;
    const float scale = scale_p[0];
    const float inv_denom = 1.0f / (24.0f + 1e-6f);

    // --- power table: tab[n] = exp(-scale*n) ---
    if (threadIdx.x < 26)
        tab[threadIdx.x] = __expf(-scale * (float)threadIdx.x);

    const float r      = __expf(-scale);
    const float inv1mr = 1.0f / (1.0f - r);

    // --- load my wave's 512 bits; keep ballot masks (wave-uniform scalars) ---
    unsigned long long m[8];
    unsigned mycnt = 0;
    #pragma unroll
    for (int rr = 0; rr < 8; ++rr) {
        long t = wbase + (long)rr * 64 + lane;
        int b = (t < (long)T) ? seq[t] : 0;
        m[rr] = __ballot(b != 0);
        mycnt += (unsigned)__popcll(m[rr]);
    }
    if (lane == 0) wsum[wid] = mycnt;

    // --- redundant reduction of preceding block sums (L2-hot) ---
    unsigned p = 0;
    for (int i = (int)threadIdx.x; i < bid; i += 256) p += blk_sums[i];
    #pragma unroll
    for (int off = 32; off; off >>= 1) p += __shfl_down(p, off, 64);
    if (lane == 0) bpart[wid] = p;
    __syncthreads();   // publishes wsum/bpart AND tab

    unsigned run = bpart[0] + bpart[1] + bpart[2] + bpart[3];
    for (int w = 0; w < wid; ++w) run += wsum[w];

    const unsigned long long le_mask = (lane == 63) ? ~0ULL : ((2ULL << lane) - 1ULL);

    for (int rnd = 0; rnd < 8; ++rnd) {
        const long rbase = wbase + (long)rnd * 64;
        const long t = rbase + lane;

        unsigned ones_incl = run + (unsigned)__popcll(m[rnd] & le_mask);

        // counter = (t+1)*d0 + ones*(d1-d0)  (exact for this data)
        float c   = (float)(t + 1) * d0 + (float)ones_incl * dd;
        float z   = 10.0f * (c * inv_denom - 0.5f);
        float sig = 1.0f / (1.0f + __expf(-z));
        float cs  = sig * 24.0f;                 // in [0, 24]

        int   k = (int)cs;                       // floor (cs >= 0); k in [0,24]
        float f = cs - (float)k;
        float a = __expf(-scale * f);
        float b = __expf(-scale * (1.0f - f));

        float sum = (a * (1.0f - tab[k + 1]) + b * (1.0f - tab[24 - k])) * inv1mr;
        float inv = 1.0f / sum;
        float ai = a * inv, bi = b * inv;

        // Per-wave private LDS slice: no block barrier needed.
        #pragma unroll
        for (int j = 0; j < MAXO; ++j) {
            int   idx = (int)fabsf((float)j - cs);       // floor(|j-c|)
            float mlt = (j <= k) ? ai : bi;
            stage[wid][lane * MAXO + j] = mlt * tab[idx]; // stride 25: conflict-free
        }

        long rem = (long)T - rbase;
        int V = (rem >= 64) ? 64 : (rem < 0 ? 0 : (int)rem);

        if (V == 64) {
            float4* o4 = (float4*)(out + rbase * MAXO);            // 6400B-aligned
            const float4* s4 = (const float4*)&stage[wid][0];
            #pragma unroll
            for (int s = 0; s < 6; ++s)
                o4[s * 64 + lane] = s4[s * 64 + lane];
            if (lane < 16) o4[384 + lane] = s4[384 + lane];
        } else if (V > 0) {
            int F = V * MAXO;
            for (int fi = lane; fi < F; fi += 64)
                out[rbase * MAXO + fi] = stage[wid][fi];
        }

        run += (unsigned)__popcll(m[rnd]);
    }
}

// ---------------------------------------------------------------------------
extern "C" void kernel_launch(void* const* d_in, const int* in_sizes, int n_in,
                              void* d_out, int out_size, void* d_ws, size_t ws_size,
                              hipStream_t stream)
{
    const float* delta   = (const float*)d_in[0];
    const float* scale_p = (const float*)d_in[1];
    const int*   seq     = (const int*)d_in[2];
    const int T = in_sizes[2];
    const int nblocks = (T + BCHUNK - 1) / BCHUNK;

    unsigned* blk_sums = (unsigned*)d_ws;   // nblocks * 4 bytes

    pda_sums<<<nblocks, 256, 0, stream>>>(seq, blk_sums, T);
    pda_main<<<nblocks, 256, 0, stream>>>(seq, blk_sums, delta, scale_p,
                                          (float*)d_out, T);
}